// Round 11
// baseline (296.861 us; speedup 1.0000x reference)
//
#include <hip/hip_runtime.h>
#include <math.h>

#pragma clang fp contract(off)

#define Bn 2
#define Vn 8000
#define Fn 1500
#define Hn 128
#define Wn 128
#define EPS_AREA_F 1e-8f
#define EPS_Z_F 1e-4f
#define NSEG 8              // waves per raster block
#define NSLICE 8            // raster blocks per tile (face-range slices)
#define TPB (NSEG * 64)     // 512
#define MAXR 192            // max faces per slice range (1500/8 -> 188)

// ws layout:
//   recS    : float4[Bn*Fn*3]          @ 0        (144000 B)
//   bboxT   : u32[Bn*Fn]               @ 144000   (12000 B)
//   keyslice: u64[Bn*16384*NSLICE]     @ 156000   (2 MB)  — every slot written
//             exactly once per call (dense), so no init needed.
//   counters: u32[Bn*256]              @ 2253152  (2 KB)  — zeroed by proj_kernel
//             in the same call (no cross-call state).

#define KEY_OFF 156000
#define CNT_OFF 2253152

__global__ void proj_kernel(const float* __restrict__ verts, const float* __restrict__ R,
                            const float* __restrict__ T, const float* __restrict__ focal,
                            const int* __restrict__ faces,
                            float4* __restrict__ recS, unsigned* __restrict__ bboxT,
                            unsigned* __restrict__ counters) {
    int t = blockIdx.x * blockDim.x + threadIdx.x;
    if (t < Bn * 256) counters[t] = 0u;          // per-tile arrival counters
    if (t >= Bn * Fn) return;
    int b = t / Fn;
    int f = t - b * Fn;
    const float* Rb = R + b * 9;
    const float* Tb = T + b * 3;
    float fo = focal[0];
    float X[3], Y[3], Z[3];
    for (int k = 0; k < 3; ++k) {
        int vi = faces[f * 3 + k];
        const float* v = verts + ((size_t)b * Vn + vi) * 3;
        float v0 = v[0], v1 = v[1], v2 = v[2];
        // exact reference einsum op order, contraction off
        float vx = v0 * Rb[0] + v1 * Rb[3] + v2 * Rb[6] + Tb[0];
        float vy = v0 * Rb[1] + v1 * Rb[4] + v2 * Rb[7] + Tb[1];
        float vz = v0 * Rb[2] + v1 * Rb[5] + v2 * Rb[8] + Tb[2];
        X[k] = (fo * vx) / vz;
        Y[k] = (fo * vy) / vz;
        Z[k] = vz;
    }
    float area = (X[2] - X[0]) * (Y[1] - Y[0]) - (Y[2] - Y[0]) * (X[1] - X[0]);
    float as = (fabsf(area) > EPS_AREA_F) ? area : EPS_AREA_F;
    recS[t * 3 + 0] = make_float4(X[0], Y[0], X[1], Y[1]);
    recS[t * 3 + 1] = make_float4(X[2], Y[2], as, Z[0]);
    recS[t * 3 + 2] = make_float4(Z[1], Z[2], 0.0f, 0.0f);

    unsigned pk = 0xFFFFFFFFu;   // sentinel: face can never be 'inside' -> exact skip
    if (fabsf(area) > EPS_AREA_F) {
        float xmin = fminf(X[0], fminf(X[1], X[2]));
        float xmax = fmaxf(X[0], fmaxf(X[1], X[2]));
        float ymin = fminf(Y[0], fminf(Y[1], Y[2]));
        float ymax = fmaxf(Y[0], fmaxf(Y[1], Y[2]));
        const float D = 0.02f;   // pad >> max fp sign-flip dilation (~1e-5 NDC)
        float wlo = ceilf(64.0f * (1.0f - xmax - D) - 0.5f);
        float whi = floorf(64.0f * (1.0f - xmin + D) - 0.5f);
        float hlo = ceilf(64.0f * (1.0f - ymax - D) - 0.5f);
        float hhi = floorf(64.0f * (1.0f - ymin + D) - 0.5f);
        wlo = fmaxf(wlo, 0.0f); whi = fminf(whi, 127.0f);
        hlo = fmaxf(hlo, 0.0f); hhi = fminf(hhi, 127.0f);
        // NaN-safe: NaN comparisons fail -> skip; +-inf clamps to full screen.
        if ((wlo <= whi) && (hlo <= hhi)) {
            int tx0 = (int)wlo >> 3, tx1 = (int)whi >> 3;
            int ty0 = (int)hlo >> 3, ty1 = (int)hhi >> 3;
            pk = (unsigned)tx0 | ((unsigned)tx1 << 8) |
                 ((unsigned)ty0 << 16) | ((unsigned)ty1 << 24);
        }
    }
    bboxT[t] = pk;
}

// Block = (batch, tile, slice). R9-proven phases: lane-parallel bbox test ->
// ballot-compact survivor list -> parallel-stage records into LDS -> 8 waves
// rasterize. Then last-arriver epilogue: release-store 64 dense keys,
// acq_rel counter bump; the 8th block acquire-loads all 8x64 slots (L2-hot),
// merges (order-independent min), and writes the final outputs.
// key=(zp_bits<<32)|f = min-z then min-idx = exact argmin-first semantics.
__global__ __launch_bounds__(TPB)
void raster_kernel(const float4* __restrict__ recS, const unsigned* __restrict__ bboxT,
                   unsigned long long* __restrict__ keyslice,
                   unsigned* __restrict__ counters, float* __restrict__ out) {
    __shared__ unsigned short smList[MAXR];           //   384 B
    __shared__ float4 smRec[MAXR * 3];                //  9216 B
    __shared__ unsigned long long smK[NSEG * 64];     //  4096 B
    __shared__ int smCount;
    __shared__ int smLast;

    int tid = threadIdx.x;
    int lane = tid & 63;
    int seg = tid >> 6;
    int blk = blockIdx.x;                 // ((b*256 + tile)*NSLICE + slice)
    int slice = blk & (NSLICE - 1);
    int bt_ = blk >> 3;
    int b = bt_ >> 8;
    int tile = bt_ & 255;
    int ty = tile >> 4, tx = tile & 15;

    int lo = (slice * Fn) >> 3;
    int n = (((slice + 1) * Fn) >> 3) - lo;   // <= 188

    if (tid == 0) { smCount = 0; smLast = 0; }
    __syncthreads();

    // lane-parallel bbox test: one thread per face in range
    {
        bool pass = false;
        if (tid < n) {
            unsigned pk = bboxT[(size_t)b * Fn + lo + tid];
            if (pk != 0xFFFFFFFFu) {
                int tx0 = pk & 0xFF, tx1 = (pk >> 8) & 0xFF;
                int ty0 = (pk >> 16) & 0xFF, ty1 = (pk >> 24) & 0xFF;
                pass = (tx >= tx0) & (tx <= tx1) & (ty >= ty0) & (ty <= ty1);
            }
        }
        unsigned long long m = __ballot(pass);
        int cnt = (int)__popcll(m);
        if (cnt) {
            int base = 0;
            if (lane == 0) base = atomicAdd(&smCount, cnt);
            base = __shfl(base, 0);
            if (pass) {
                int pos = (int)__popcll(m & ((1ull << lane) - 1ull));
                smList[base + pos] = (unsigned short)(lo + tid);
            }
        }
    }
    __syncthreads();
    int cnt = smCount;

    // parallel-stage survivor records (3 x float4 each) into LDS
    for (int i = tid; i < cnt * 3; i += TPB) {
        int f = smList[i / 3];
        smRec[i] = recS[((size_t)b * Fn + f) * 3 + (i - (i / 3) * 3)];
    }
    __syncthreads();

    int h = (ty << 3) | (lane >> 3);
    int w = (tx << 3) | (lane & 7);
    float px = 1.0f - (2.0f * ((float)w + 0.5f)) / (float)Wn;
    float py = 1.0f - (2.0f * ((float)h + 0.5f)) / (float)Hn;

    unsigned long long best = ~0ull;
    for (int j = seg; j < cnt; j += NSEG) {
        float4 q0 = smRec[j * 3 + 0];     // wave-uniform LDS broadcast
        float4 q1 = smRec[j * 3 + 1];
        float4 q2 = smRec[j * 3 + 2];
        int f = smList[j];
        float x0 = q0.x, y0 = q0.y, x1 = q0.z, y1 = q0.w;
        float x2 = q1.x, y2 = q1.y, as = q1.z, z0 = q1.w;
        float z1 = q2.x, z2 = q2.y;
        // exact reference op order (_edge), contraction off
        float w0 = (px - x1) * (y2 - y1) - (py - y1) * (x2 - x1);
        float w1 = (px - x2) * (y0 - y2) - (py - y2) * (x0 - x2);
        float w2 = (px - x0) * (y1 - y0) - (py - y0) * (x1 - x0);
        // sign-only inside: w/as >= 0 iff sign matches (division preserves sign)
        bool ins = (as > 0.0f) ? (w0 >= 0.0f && w1 >= 0.0f && w2 >= 0.0f)
                               : (w0 <= 0.0f && w1 <= 0.0f && w2 <= 0.0f);
        // (listed faces all have |area| > EPS_AREA, so areaok is implied)
        if (ins) {
            float b0 = w0 / as;
            float b1 = w1 / as;
            float b2 = w2 / as;
            float zp = (b0 * z0 + b1 * z1) + b2 * z2;
            if (zp > EPS_Z_F) {
                unsigned long long ck =
                    ((unsigned long long)__float_as_uint(zp) << 32) | (unsigned)f;
                if (ck < best) best = ck;   // min z, then min idx = argmin-first
            }
        }
    }
    smK[seg * 64 + lane] = best;
    __syncthreads();

    if (tid < 64) {
        unsigned long long bk = smK[tid];
        #pragma unroll
        for (int s = 1; s < NSEG; ++s) {
            unsigned long long k = smK[s * 64 + tid];
            if (k < bk) bk = k;
        }
        int p = (b << 14) + (((ty << 3) | (tid >> 3)) * Wn) + ((tx << 3) | (tid & 7));
        // release, agent scope: visible device-wide (cross-XCD) before the
        // counter bump below can be observed.
        __hip_atomic_store(&keyslice[(size_t)p * NSLICE + slice], bk,
                           __ATOMIC_RELEASE, __HIP_MEMORY_SCOPE_AGENT);
    }
    __syncthreads();          // all 64 release-stores issued & completed

    if (tid == 0) {
        unsigned old = __hip_atomic_fetch_add(&counters[(size_t)b * 256 + tile], 1u,
                                              __ATOMIC_ACQ_REL, __HIP_MEMORY_SCOPE_AGENT);
        smLast = (old == NSLICE - 1);
    }
    __syncthreads();

    if (smLast && tid < 64) {
        // last arriver for this tile: merge 8 slices, run epilogue for 64 pixels
        int hh = (ty << 3) | (tid >> 3);
        int ww = (tx << 3) | (tid & 7);
        float ppx = 1.0f - (2.0f * ((float)ww + 0.5f)) / (float)Wn;
        float ppy = 1.0f - (2.0f * ((float)hh + 0.5f)) / (float)Hn;
        int p = (b << 14) + hh * Wn + ww;
        const unsigned long long* ks = keyslice + (size_t)p * NSLICE;
        unsigned long long bk = ~0ull;
        #pragma unroll
        for (int s = 0; s < NSLICE; ++s) {
            unsigned long long k = __hip_atomic_load(&ks[s], __ATOMIC_ACQUIRE,
                                                     __HIP_MEMORY_SCOPE_AGENT);
            if (k < bk) bk = k;
        }
        const int HWB = Bn * Hn * Wn;
        float o_idx = -1.0f, o_z = -1.0f, ob0 = -1.0f, ob1 = -1.0f, ob2 = -1.0f, o_d = -1.0f;
        if (bk != ~0ull) {
            int f = (int)(bk & 0xFFFFFFFFu);
            float4 q0 = recS[((size_t)b * Fn + f) * 3 + 0];
            float4 q1 = recS[((size_t)b * Fn + f) * 3 + 1];
            float x0 = q0.x, y0 = q0.y, x1 = q0.z, y1 = q0.w;
            float x2 = q1.x, y2 = q1.y, as = q1.z;
            // winner bary: exactly the reference phase-2 expressions
            float w0 = (ppx - x1) * (y2 - y1) - (ppy - y1) * (x2 - x1);
            float w1 = (ppx - x2) * (y0 - y2) - (ppy - y2) * (x0 - x2);
            float w2 = (ppx - x0) * (y1 - y0) - (ppy - y0) * (x1 - x0);
            float c0 = w0 / as, c1 = w1 / as, c2 = w2 / as;
            auto segd = [&](float ax, float ay, float bx, float by) -> float {
                float dx = bx - ax, dy = by - ay;
                float l2 = dx * dx + dy * dy;
                l2 = (l2 > 1e-12f) ? l2 : 1e-12f;
                float q = ((ppx - ax) * dx + (ppy - ay) * dy) / l2;
                q = (q < 0.0f) ? 0.0f : ((q > 1.0f) ? 1.0f : q);
                float ex = (ax + q * dx) - ppx;
                float ey = (ay + q * dy) - ppy;
                return ex * ex + ey * ey;
            };
            float d2 = fminf(fminf(segd(x0, y0, x1, y1), segd(x1, y1, x2, y2)),
                             segd(x2, y2, x0, y0));
            bool inside_b = (c0 >= 0.0f) && (c1 >= 0.0f) && (c2 >= 0.0f);
            o_idx = (float)f;
            o_z = __uint_as_float((unsigned)(bk >> 32));
            ob0 = c0; ob1 = c1; ob2 = c2;
            o_d = inside_b ? -d2 : d2;
        }
        out[p] = o_idx;
        out[HWB + p] = o_z;
        out[2 * HWB + p * 3 + 0] = ob0;
        out[2 * HWB + p * 3 + 1] = ob1;
        out[2 * HWB + p * 3 + 2] = ob2;
        out[5 * HWB + p] = o_d;
    }
}

extern "C" void kernel_launch(void* const* d_in, const int* in_sizes, int n_in,
                              void* d_out, int out_size, void* d_ws, size_t ws_size,
                              hipStream_t stream) {
    const float* verts = (const float*)d_in[0];
    const float* R     = (const float*)d_in[1];
    const float* T     = (const float*)d_in[2];
    const float* focal = (const float*)d_in[3];
    const int*   faces = (const int*)d_in[4];
    float* out = (float*)d_out;
    char* ws = (char*)d_ws;
    float4* recS                 = (float4*)(ws);
    unsigned* bboxT              = (unsigned*)(ws + 144000);
    unsigned long long* keyslice = (unsigned long long*)(ws + KEY_OFF);
    unsigned* counters           = (unsigned*)(ws + CNT_OFF);

    hipLaunchKernelGGL(proj_kernel, dim3((Bn * Fn + 255) / 256), dim3(256), 0, stream,
                       verts, R, T, focal, faces, recS, bboxT, counters);
    hipLaunchKernelGGL(raster_kernel, dim3(Bn * 256 * NSLICE), dim3(TPB), 0, stream,
                       recS, bboxT, keyslice, counters, out);
}

// Round 13
// 84.989 us; speedup vs baseline: 3.4929x; 3.4929x over previous
//
#include <hip/hip_runtime.h>
#include <math.h>

#pragma clang fp contract(off)

#define Bn 2
#define Vn 8000
#define Fn 1500
#define Hn 128
#define Wn 128
#define EPS_AREA_F 1e-8f
#define EPS_Z_F 1e-4f
#define NSEG 8              // waves per raster block
#define NSLICE 8            // raster blocks per tile (face-range slices)
#define TPB (NSEG * 64)     // 512
#define MAXR 192            // max faces per slice range (1500/8 = 187.5 -> 188)

// ws layout:
//   recS    : float4[Bn*Fn*3]          @ 0        (144000 B)
//   bboxT   : u32[Bn*Fn]               @ 144000   (12000 B)
//   keyslice: u64[Bn*16384*NSLICE]     @ 156000   (2 MB) — written unconditionally,
//                                                  no init, no atomics, deterministic.

__global__ void proj_kernel(const float* __restrict__ verts, const float* __restrict__ R,
                            const float* __restrict__ T, const float* __restrict__ focal,
                            const int* __restrict__ faces,
                            float4* __restrict__ recS, unsigned* __restrict__ bboxT) {
    int t = blockIdx.x * blockDim.x + threadIdx.x;
    if (t >= Bn * Fn) return;
    int b = t / Fn;
    int f = t - b * Fn;
    const float* Rb = R + b * 9;
    const float* Tb = T + b * 3;
    float fo = focal[0];
    float X[3], Y[3], Z[3];
    for (int k = 0; k < 3; ++k) {
        int vi = faces[f * 3 + k];
        const float* v = verts + ((size_t)b * Vn + vi) * 3;
        float v0 = v[0], v1 = v[1], v2 = v[2];
        float vx = v0 * Rb[0] + v1 * Rb[3] + v2 * Rb[6] + Tb[0];
        float vy = v0 * Rb[1] + v1 * Rb[4] + v2 * Rb[7] + Tb[1];
        float vz = v0 * Rb[2] + v1 * Rb[5] + v2 * Rb[8] + Tb[2];
        X[k] = (fo * vx) / vz;
        Y[k] = (fo * vy) / vz;
        Z[k] = vz;
    }
    float area = (X[2] - X[0]) * (Y[1] - Y[0]) - (Y[2] - Y[0]) * (X[1] - X[0]);
    float as = (fabsf(area) > EPS_AREA_F) ? area : EPS_AREA_F;
    recS[t * 3 + 0] = make_float4(X[0], Y[0], X[1], Y[1]);
    recS[t * 3 + 1] = make_float4(X[2], Y[2], area, as);
    recS[t * 3 + 2] = make_float4(Z[0], Z[1], Z[2], 0.0f);

    unsigned pk = 0xFFFFFFFFu;   // sentinel: face can never be 'inside' -> exact skip
    if (fabsf(area) > EPS_AREA_F) {
        float xmin = fminf(X[0], fminf(X[1], X[2]));
        float xmax = fmaxf(X[0], fmaxf(X[1], X[2]));
        float ymin = fminf(Y[0], fminf(Y[1], Y[2]));
        float ymax = fmaxf(Y[0], fmaxf(Y[1], Y[2]));
        const float D = 0.02f;   // pad >> max fp sign-flip dilation (~1e-5 NDC)
        float wlo = ceilf(64.0f * (1.0f - xmax - D) - 0.5f);
        float whi = floorf(64.0f * (1.0f - xmin + D) - 0.5f);
        float hlo = ceilf(64.0f * (1.0f - ymax - D) - 0.5f);
        float hhi = floorf(64.0f * (1.0f - ymin + D) - 0.5f);
        wlo = fmaxf(wlo, 0.0f); whi = fminf(whi, 127.0f);
        hlo = fmaxf(hlo, 0.0f); hhi = fminf(hhi, 127.0f);
        // NaN-safe: NaN comparisons fail -> skip; +-inf clamps to full screen.
        if ((wlo <= whi) && (hlo <= hhi)) {
            int tx0 = (int)wlo >> 3, tx1 = (int)whi >> 3;
            int ty0 = (int)hlo >> 3, ty1 = (int)hhi >> 3;
            pk = (unsigned)tx0 | ((unsigned)tx1 << 8) |
                 ((unsigned)ty0 << 16) | ((unsigned)ty1 << 24);
        }
    }
    bboxT[t] = pk;
}

// Block = (batch, tile, slice). Slice owns face range [(s*Fn)>>3, ((s+1)*Fn)>>3)
// (<=188 faces). Lane-parallel bbox test -> ballot-compact survivor list ->
// parallel-stage survivor records into LDS -> 8 waves loop over LDS.
// List order is wave-arrival nondeterministic, but each block processes its
// ENTIRE block-local list and min-over-u64-keys is order-independent, so the
// result is deterministic (R6's bug was partitioning differently-ordered lists
// across blocks — never done here).
__global__ __launch_bounds__(TPB)
void raster_kernel(const float4* __restrict__ recS, const unsigned* __restrict__ bboxT,
                   unsigned long long* __restrict__ keyslice) {
    __shared__ unsigned short smList[MAXR];           //   384 B
    __shared__ float4 smRec[MAXR * 3];                //  9216 B
    __shared__ unsigned long long smK[NSEG * 64];     //  4096 B
    __shared__ int smCount;

    int tid = threadIdx.x;
    int lane = tid & 63;
    int seg = tid >> 6;
    int blk = blockIdx.x;                 // ((b*256 + tile)*NSLICE + slice)
    int slice = blk & (NSLICE - 1);
    int bt_ = blk >> 3;
    int b = bt_ >> 8;
    int tile = bt_ & 255;
    int ty = tile >> 4, tx = tile & 15;

    int lo = (slice * Fn) >> 3;
    int hi = ((slice + 1) * Fn) >> 3;
    int n = hi - lo;                      // <= 188

    if (tid == 0) smCount = 0;
    __syncthreads();

    // lane-parallel bbox test: one thread per face in range
    {
        bool pass = false;
        if (tid < n) {
            unsigned pk = bboxT[(size_t)b * Fn + lo + tid];
            if (pk != 0xFFFFFFFFu) {
                int tx0 = pk & 0xFF, tx1 = (pk >> 8) & 0xFF;
                int ty0 = (pk >> 16) & 0xFF, ty1 = (pk >> 24) & 0xFF;
                pass = (tx >= tx0) & (tx <= tx1) & (ty >= ty0) & (ty <= ty1);
            }
        }
        unsigned long long m = __ballot(pass);
        int cnt = (int)__popcll(m);
        if (cnt) {
            int base = 0;
            if (lane == 0) base = atomicAdd(&smCount, cnt);
            base = __shfl(base, 0);
            if (pass) {
                int pos = (int)__popcll(m & ((1ull << lane) - 1ull));
                smList[base + pos] = (unsigned short)(lo + tid);
            }
        }
    }
    __syncthreads();
    int cnt = smCount;

    // parallel-stage survivor records (3 x float4 each) into LDS: one vmcnt wait
    for (int i = tid; i < cnt * 3; i += TPB) {
        int f = smList[i / 3];
        smRec[i] = recS[((size_t)b * Fn + f) * 3 + (i - (i / 3) * 3)];
    }
    __syncthreads();

    int h = (ty << 3) | (lane >> 3);
    int w = (tx << 3) | (lane & 7);
    float px = 1.0f - (2.0f * ((float)w + 0.5f)) / (float)Wn;
    float py = 1.0f - (2.0f * ((float)h + 0.5f)) / (float)Hn;

    unsigned long long best = ~0ull;
    for (int j = seg; j < cnt; j += NSEG) {
        float4 q0 = smRec[j * 3 + 0];     // wave-uniform LDS broadcast
        float4 q1 = smRec[j * 3 + 1];
        float4 q2 = smRec[j * 3 + 2];
        int f = smList[j];
        float x0 = q0.x, y0 = q0.y, x1 = q0.z, y1 = q0.w;
        float x2 = q1.x, y2 = q1.y, as = q1.w;
        // exact reference op order (_edge), contraction off
        float w0 = (px - x1) * (y2 - y1) - (py - y1) * (x2 - x1);
        float w1 = (px - x2) * (y0 - y2) - (py - y2) * (x0 - x2);
        float w2 = (px - x0) * (y1 - y0) - (py - y0) * (x1 - x0);
        // sign-only inside: w/as >= 0 iff sign matches (division preserves sign)
        bool ins = (as > 0.0f) ? (w0 >= 0.0f && w1 >= 0.0f && w2 >= 0.0f)
                               : (w0 <= 0.0f && w1 <= 0.0f && w2 <= 0.0f);
        // (listed faces all have |area| > EPS_AREA, so areaok is implied)
        if (ins) {
            float b0 = w0 / as;
            float b1 = w1 / as;
            float b2 = w2 / as;
            float zp = (b0 * q2.x + b1 * q2.y) + b2 * q2.z;
            if (zp > EPS_Z_F) {
                unsigned long long ck =
                    ((unsigned long long)__float_as_uint(zp) << 32) | (unsigned)f;
                if (ck < best) best = ck;   // min z, then min idx = argmin-first
            }
        }
    }
    smK[seg * 64 + lane] = best;
    __syncthreads();

    if (tid < 64) {
        unsigned long long bk = smK[tid];
        #pragma unroll
        for (int s = 1; s < NSEG; ++s) {
            unsigned long long k = smK[s * 64 + tid];
            if (k < bk) bk = k;
        }
        int hh = (ty << 3) | (tid >> 3);
        int ww = (tx << 3) | (tid & 7);
        int p = (b << 14) + hh * Wn + ww;
        keyslice[(size_t)p * NSLICE + slice] = bk;   // unconditional: no init needed
    }
}

__global__ __launch_bounds__(256)
void writer_kernel(const float4* __restrict__ recS,
                   const unsigned long long* __restrict__ keyslice,
                   float* __restrict__ out) {
    int p = blockIdx.x * blockDim.x + threadIdx.x;
    if (p >= Bn * Hn * Wn) return;
    int b = p >> 14;
    int hw = p & 16383;
    int h = hw >> 7;
    int w = hw & 127;
    float px = 1.0f - (2.0f * ((float)w + 0.5f)) / (float)Wn;
    float py = 1.0f - (2.0f * ((float)h + 0.5f)) / (float)Hn;
    const unsigned long long* ks = keyslice + (size_t)p * NSLICE;
    unsigned long long bk = ks[0];
    #pragma unroll
    for (int s = 1; s < NSLICE; ++s) {
        unsigned long long k = ks[s];
        if (k < bk) bk = k;
    }
    const float4* rb = recS + (size_t)b * Fn * 3;
    const int HWB = Bn * Hn * Wn;
    float o_idx = -1.0f, o_z = -1.0f, ob0 = -1.0f, ob1 = -1.0f, ob2 = -1.0f, o_d = -1.0f;
    if (bk != ~0ull) {
        int f = (int)(bk & 0xFFFFFFFFu);
        float4 q0 = rb[(size_t)f * 3 + 0];
        float4 q1 = rb[(size_t)f * 3 + 1];
        float x0 = q0.x, y0 = q0.y, x1 = q0.z, y1 = q0.w;
        float x2 = q1.x, y2 = q1.y, as = q1.w;
        // winner bary: exactly the reference phase-2 expressions
        float w0 = (px - x1) * (y2 - y1) - (py - y1) * (x2 - x1);
        float w1 = (px - x2) * (y0 - y2) - (py - y2) * (x0 - x2);
        float w2 = (px - x0) * (y1 - y0) - (py - y0) * (x1 - x0);
        float c0 = w0 / as, c1 = w1 / as, c2 = w2 / as;
        auto segd = [&](float ax, float ay, float bx, float by) -> float {
            float dx = bx - ax, dy = by - ay;
            float l2 = dx * dx + dy * dy;
            l2 = (l2 > 1e-12f) ? l2 : 1e-12f;
            float q = ((px - ax) * dx + (py - ay) * dy) / l2;
            q = (q < 0.0f) ? 0.0f : ((q > 1.0f) ? 1.0f : q);
            float ex = (ax + q * dx) - px;
            float ey = (ay + q * dy) - py;
            return ex * ex + ey * ey;
        };
        float d2 = fminf(fminf(segd(x0, y0, x1, y1), segd(x1, y1, x2, y2)),
                         segd(x2, y2, x0, y0));
        bool inside_b = (c0 >= 0.0f) && (c1 >= 0.0f) && (c2 >= 0.0f);
        o_idx = (float)f;
        o_z = __uint_as_float((unsigned)(bk >> 32));
        ob0 = c0; ob1 = c1; ob2 = c2;
        o_d = inside_b ? -d2 : d2;
    }
    out[p] = o_idx;
    out[HWB + p] = o_z;
    out[2 * HWB + p * 3 + 0] = ob0;
    out[2 * HWB + p * 3 + 1] = ob1;
    out[2 * HWB + p * 3 + 2] = ob2;
    out[5 * HWB + p] = o_d;
}

extern "C" void kernel_launch(void* const* d_in, const int* in_sizes, int n_in,
                              void* d_out, int out_size, void* d_ws, size_t ws_size,
                              hipStream_t stream) {
    const float* verts = (const float*)d_in[0];
    const float* R     = (const float*)d_in[1];
    const float* T     = (const float*)d_in[2];
    const float* focal = (const float*)d_in[3];
    const int*   faces = (const int*)d_in[4];
    float* out = (float*)d_out;
    char* ws = (char*)d_ws;
    float4* recS                 = (float4*)(ws);
    unsigned* bboxT              = (unsigned*)(ws + 144000);
    unsigned long long* keyslice = (unsigned long long*)(ws + 156000);

    hipLaunchKernelGGL(proj_kernel, dim3((Bn * Fn + 255) / 256), dim3(256), 0, stream,
                       verts, R, T, focal, faces, recS, bboxT);
    hipLaunchKernelGGL(raster_kernel, dim3(Bn * 256 * NSLICE), dim3(TPB), 0, stream,
                       recS, bboxT, keyslice);
    hipLaunchKernelGGL(writer_kernel, dim3((Bn * Hn * Wn + 255) / 256), dim3(256),
                       0, stream, recS, keyslice, out);
}